// Round 1
// baseline (1235.892 us; speedup 1.0000x reference)
//
#include <hip/hip_runtime.h>

#define N_NODES 100000
#define N_EDGES 400000
#define N_GRAPHS 2048
#define HID 128
#define NLAYER 4
#define TOUT 5
#define EPSV 1e-5f
#define SLOPE 0.2f

typedef float v4f __attribute__((ext_vector_type(4)));
typedef __bf16 v8bf __attribute__((ext_vector_type(8)));
typedef short v8s __attribute__((ext_vector_type(8)));

static __device__ __forceinline__ unsigned short f2bf_bits(float f){
  unsigned u = __builtin_bit_cast(unsigned, f);
  unsigned r = u + 0x7fffu + ((u >> 16) & 1u);
  return (unsigned short)(r >> 16);
}
static __device__ __forceinline__ float bfbits2f(unsigned short s){
  unsigned u = ((unsigned)s) << 16;
  return __builtin_bit_cast(float, u);
}

// h = x @ node_w + node_b
__global__ void k_hinit(const float* __restrict__ x, const float* __restrict__ nw,
                        const float* __restrict__ nb, float* __restrict__ hbuf){
  int n = blockIdx.x; int c = threadIdx.x;
  float acc = nb[c];
  #pragma unroll
  for(int f=0; f<7; ++f) acc += x[n*7+f]*nw[f*HID+c];
  hbuf[n*HID+c] = acc;
}

// small projection matrices: Me[3][16], be[16] such that a_e[e][l*4+h] = ea@Me + be
__global__ void k_prep(const float* __restrict__ gat_edge_w, const float* __restrict__ att_edge,
                       const float* __restrict__ edge_w, const float* __restrict__ edge_b,
                       float* __restrict__ mebuf){
  __shared__ float Ve[128*16];
  int t = threadIdx.x;
  for(int id=t; id<2048; id+=256){
    int k = id>>4, li = id&15, l = li>>2, hh = li&3;
    const float* gw = gat_edge_w + l*16384 + k*128 + hh*32;
    const float* at = att_edge + l*128 + hh*32;
    float s = 0.f;
    #pragma unroll
    for(int c=0;c<32;++c) s += gw[c]*at[c];
    Ve[k*16+li] = s;
  }
  __syncthreads();
  if(t < 48){
    int f = t>>4, li = t&15;
    float s=0.f;
    for(int k=0;k<128;++k) s += edge_w[f*128+k]*Ve[k*16+li];
    mebuf[f*16+li] = s;
  } else if (t < 64){
    int li = t-48; float s=0.f;
    for(int k=0;k<128;++k) s += edge_b[k]*Ve[k*16+li];
    mebuf[48+li] = s;
  }
}

// swizzle gat_lin_w into MFMA B-fragment order, split into bf16 hi/lo
__global__ void k_wswz(const float* __restrict__ W, unsigned short* __restrict__ whi,
                       unsigned short* __restrict__ wlo){
  int idx = blockIdx.x*256 + threadIdx.x; // 0..65535 == l*16384 + k*128 + c
  int l = idx>>14, k = (idx>>7)&127, c = idx&127;
  float w = W[idx];
  unsigned short hi = f2bf_bits(w);
  unsigned short lo = f2bf_bits(w - bfbits2f(hi));
  int kb=k>>5, quad=(k>>3)&3, j=k&7, cg=c>>4, r=c&15, lane=quad*16+r;
  int dst = ((l*4+kb)*8+cg)*512 + lane*8 + j;
  whi[dst]=hi; wlo[dst]=lo;
}

// per real edge: a_e for all 4 layers x 4 heads; accumulate deg + sums for self-loop mean
__global__ void k_edge(const int* __restrict__ ei, const float* __restrict__ ea,
                       const float* __restrict__ mebuf, float* __restrict__ ae,
                       float* __restrict__ aeloop, int* __restrict__ deg){
  int e = blockIdx.x*256 + threadIdx.x;
  if(e >= N_EDGES) return;
  int dst = ei[N_EDGES + e];
  float a0 = ea[e*3], a1 = ea[e*3+1], a2 = ea[e*3+2];
  #pragma unroll
  for(int i=0;i<16;++i){
    float v = mebuf[48+i] + a0*mebuf[i] + a1*mebuf[16+i] + a2*mebuf[32+i];
    ae[e*16+i] = v;
    atomicAdd(&aeloop[dst*16+i], v);
  }
  atomicAdd(&deg[dst], 1);
}

__global__ void k_aediv(float* __restrict__ aeloop, const int* __restrict__ deg){
  int idx = blockIdx.x*256+threadIdx.x;
  if(idx >= N_NODES*16) return;
  int d = deg[idx>>4];
  aeloop[idx] = aeloop[idx] / (float)(d>1?d:1);
}

// exclusive scan of deg -> rowptr (3 phases, chunk=1024)
__global__ void k_scan1(const int* __restrict__ deg, int* __restrict__ part){
  __shared__ int s[256];
  int t=threadIdx.x; int base = blockIdx.x*1024 + t*4;
  int sum=0;
  #pragma unroll
  for(int j=0;j<4;++j){ int i=base+j; sum += (i<N_NODES)? deg[i]:0; }
  s[t]=sum; __syncthreads();
  for(int off=128; off>0; off>>=1){ if(t<off) s[t]+=s[t+off]; __syncthreads(); }
  if(t==0) part[blockIdx.x]=s[0];
}
__global__ void k_scan2(int* __restrict__ part, int* __restrict__ rowptr, int nb){
  if(threadIdx.x==0 && blockIdx.x==0){
    int run=0;
    for(int i=0;i<nb;++i){ int v=part[i]; part[i]=run; run+=v; }
    rowptr[N_NODES]=run;
  }
}
__global__ void k_scan3(const int* __restrict__ deg, const int* __restrict__ part, int* __restrict__ rowptr){
  __shared__ int s[256];
  int t=threadIdx.x; int base = blockIdx.x*1024 + t*4;
  int v[4]; int sum=0; int pre[4];
  #pragma unroll
  for(int j=0;j<4;++j){ int i=base+j; v[j]=(i<N_NODES)?deg[i]:0; pre[j]=sum; sum+=v[j]; }
  s[t]=sum; __syncthreads();
  for(int off=1; off<256; off<<=1){
    int xv = (t>=off)? s[t-off]:0; __syncthreads();
    s[t]+=xv; __syncthreads();
  }
  int toff = (t>0)? s[t-1]:0;
  int g = part[blockIdx.x];
  #pragma unroll
  for(int j=0;j<4;++j){ int i=base+j; if(i<N_NODES) rowptr[i]=g+toff+pre[j]; }
}

__global__ void k_fill(const int* __restrict__ ei, const int* __restrict__ rowptr,
                       int* __restrict__ fill, int* __restrict__ csr_src, int* __restrict__ csr_eid){
  int e = blockIdx.x*256+threadIdx.x;
  if(e>=N_EDGES) return;
  int dst = ei[N_EDGES+e];
  int pos = rowptr[dst] + atomicAdd(&fill[dst],1);
  csr_src[pos] = ei[e];
  csr_eid[pos] = e;
}

// xh = h @ gat_lin_w[l]  (split-bf16 MFMA, fp32-class accuracy)
// epilogue: a_s[n,h], a_d[n,h] via quad shuffles
__global__ void k_gemm(const float* __restrict__ hbuf, const unsigned short* __restrict__ whi,
                       const unsigned short* __restrict__ wlo,
                       const float* __restrict__ att_src_l, const float* __restrict__ att_dst_l,
                       float* __restrict__ xh, float* __restrict__ as_, float* __restrict__ ad_){
  int wave = threadIdx.x>>6, lane = threadIdx.x&63;
  int row0 = blockIdx.x*64 + wave*16;
  if(row0 >= N_NODES) return;
  int q = lane>>4, r = lane&15;
  const float* hrow = hbuf + (size_t)(row0 + r)*HID;
  v8bf ahi[4], alo[4];
  #pragma unroll
  for(int kb=0;kb<4;++kb){
    const v4f* p = (const v4f*)(hrow + kb*32 + q*8);
    v4f f0 = p[0], f1 = p[1];
    #pragma unroll
    for(int j=0;j<4;++j){
      unsigned short hi = f2bf_bits(f0[j]);
      unsigned short lo = f2bf_bits(f0[j]-bfbits2f(hi));
      ahi[kb][j] = __builtin_bit_cast(__bf16, hi);
      alo[kb][j] = __builtin_bit_cast(__bf16, lo);
      unsigned short hi2 = f2bf_bits(f1[j]);
      unsigned short lo2 = f2bf_bits(f1[j]-bfbits2f(hi2));
      ahi[kb][j+4] = __builtin_bit_cast(__bf16, hi2);
      alo[kb][j+4] = __builtin_bit_cast(__bf16, lo2);
    }
  }
  v4f acc[8];
  #pragma unroll
  for(int cg=0;cg<8;++cg){
    v4f a = {0.f,0.f,0.f,0.f};
    #pragma unroll
    for(int kb=0;kb<4;++kb){
      v8bf bhi = __builtin_bit_cast(v8bf, *(const v8s*)(whi + ((kb*8+cg)*64 + lane)*8));
      v8bf blo = __builtin_bit_cast(v8bf, *(const v8s*)(wlo + ((kb*8+cg)*64 + lane)*8));
      a = __builtin_amdgcn_mfma_f32_16x16x32_bf16(ahi[kb], bhi, a, 0,0,0);
      a = __builtin_amdgcn_mfma_f32_16x16x32_bf16(ahi[kb], blo, a, 0,0,0);
      a = __builtin_amdgcn_mfma_f32_16x16x32_bf16(alo[kb], bhi, a, 0,0,0);
    }
    acc[cg]=a;
  }
  #pragma unroll
  for(int cg=0;cg<8;++cg){
    #pragma unroll
    for(int reg=0;reg<4;++reg)
      xh[(size_t)(row0 + q*4 + reg)*HID + cg*16 + r] = acc[cg][reg];
  }
  #pragma unroll
  for(int hh=0; hh<4; ++hh){
    float sl = att_src_l[hh*32 + r],  sh2 = att_src_l[hh*32+16+r];
    float dl = att_dst_l[hh*32 + r],  dh  = att_dst_l[hh*32+16+r];
    #pragma unroll
    for(int reg=0;reg<4;++reg){
      float vs = acc[2*hh][reg]*sl + acc[2*hh+1][reg]*sh2;
      float vd = acc[2*hh][reg]*dl + acc[2*hh+1][reg]*dh;
      vs += __shfl_xor(vs,1); vs += __shfl_xor(vs,2); vs += __shfl_xor(vs,4); vs += __shfl_xor(vs,8);
      vd += __shfl_xor(vd,1); vd += __shfl_xor(vd,2); vd += __shfl_xor(vd,4); vd += __shfl_xor(vd,8);
      if(r==0){
        int rr = row0 + q*4 + reg;
        as_[rr*4+hh] = vs;
        ad_[rr*4+hh] = vd;
      }
    }
  }
}

// wave-per-node: CSR softmax over incoming edges + self loop, aggregate xh,
// fused bias + BN + relu + residual, in-place h update
__global__ void k_aggr(const float* __restrict__ xh, const float* __restrict__ as_,
    const float* __restrict__ ad_, const float* __restrict__ ae, const float* __restrict__ aeloop,
    const int* __restrict__ rowptr, const int* __restrict__ csr_src, const int* __restrict__ csr_eid,
    const float* __restrict__ bias, const float* __restrict__ gamma, const float* __restrict__ beta,
    const float* __restrict__ mean, const float* __restrict__ var,
    float* __restrict__ hbuf, int layer){
  int node = blockIdx.x*4 + (threadIdx.x>>6);
  if(node >= N_NODES) return;
  int lane = threadIdx.x & 63;
  int h0 = lane>>5, h1 = 2+(lane>>5);
  int c0 = lane, c1 = lane+64;
  float ad0 = ad_[node*4+h0], ad1 = ad_[node*4+h1];
  float al0 = as_[node*4+h0] + ad0 + aeloop[node*16+layer*4+h0];
  float al1 = as_[node*4+h1] + ad1 + aeloop[node*16+layer*4+h1];
  al0 = al0>0.f ? al0 : SLOPE*al0;
  al1 = al1>0.f ? al1 : SLOPE*al1;
  int s = rowptr[node], e = rowptr[node+1];
  float m0=al0, m1=al1;
  for(int j=s;j<e;++j){
    int sr = csr_src[j]; int eid = csr_eid[j];
    float b0 = as_[sr*4+h0] + ad0 + ae[eid*16+layer*4+h0];
    float b1 = as_[sr*4+h1] + ad1 + ae[eid*16+layer*4+h1];
    b0 = b0>0.f?b0:SLOPE*b0; b1 = b1>0.f?b1:SLOPE*b1;
    m0 = fmaxf(m0,b0); m1 = fmaxf(m1,b1);
  }
  float w0 = __expf(al0-m0), w1 = __expf(al1-m1);
  float d0=w0, d1=w1;
  float acc0 = w0*xh[(size_t)node*HID+c0], acc1 = w1*xh[(size_t)node*HID+c1];
  for(int j=s;j<e;++j){
    int sr = csr_src[j]; int eid = csr_eid[j];
    float b0 = as_[sr*4+h0] + ad0 + ae[eid*16+layer*4+h0];
    float b1 = as_[sr*4+h1] + ad1 + ae[eid*16+layer*4+h1];
    b0 = b0>0.f?b0:SLOPE*b0; b1 = b1>0.f?b1:SLOPE*b1;
    float e0=__expf(b0-m0), e1=__expf(b1-m1);
    d0+=e0; d1+=e1;
    acc0 += e0*xh[(size_t)sr*HID+c0];
    acc1 += e1*xh[(size_t)sr*HID+c1];
  }
  float o0 = acc0/d0 + bias[c0];
  float o1 = acc1/d1 + bias[c1];
  o0 = (o0-mean[c0])*gamma[c0]*rsqrtf(var[c0]+EPSV)+beta[c0];
  o1 = (o1-mean[c1])*gamma[c1]*rsqrtf(var[c1]+EPSV)+beta[c1];
  float n0 = fmaxf(o0,0.f)+hbuf[(size_t)node*HID+c0];
  float n1 = fmaxf(o1,0.f)+hbuf[(size_t)node*HID+c1];
  hbuf[(size_t)node*HID+c0]=n0; hbuf[(size_t)node*HID+c1]=n1;
}

__global__ void k_gptr(const int* __restrict__ batch, int* __restrict__ gptr){
  int g = blockIdx.x*256+threadIdx.x;
  if(g > N_GRAPHS) return;
  int lo=0, hi=N_NODES;
  while(lo<hi){ int mid=(lo+hi)>>1; if(batch[mid] < g) lo=mid+1; else hi=mid; }
  gptr[g]=lo;
}

__global__ void k_pool(const float* __restrict__ hbuf, const int* __restrict__ gptr,
                       float* __restrict__ gfeat){
  int g = blockIdx.x, c = threadIdx.x;
  int s = gptr[g], e = gptr[g+1];
  float sum=0.f, mx=-3.4e38f;
  for(int i=s;i<e;++i){ float v = hbuf[(size_t)i*HID+c]; sum+=v; mx=fmaxf(mx,v); }
  int cnt = e-s;
  float meanv = sum / (float)(cnt>1?cnt:1);
  if(cnt==0) mx=0.f;
  gfeat[g*384 + c] = meanv;
  gfeat[g*384 + 128 + c] = mx;
  gfeat[g*384 + 256 + c] = sum;
}

__global__ void k_head(const float* __restrict__ gfeat, const float* __restrict__ gf,
   const float* __restrict__ gc_w, const float* __restrict__ gc_b,
   const float* __restrict__ gf1_w, const float* __restrict__ gf1_b,
   const float* __restrict__ gf2_w, const float* __restrict__ gf2_b,
   const float* __restrict__ p1_w, const float* __restrict__ p1_b,
   const float* __restrict__ p2_w, const float* __restrict__ p2_b,
   const float* __restrict__ p3_w, const float* __restrict__ p3_b,
   float* __restrict__ out){
  __shared__ float sg[384];
  __shared__ float comb[192];
  __shared__ float hid1[64];
  __shared__ float r1[128];
  __shared__ float r2[64];
  int g = blockIdx.x, t = threadIdx.x;
  for(int i=t;i<384;i+=128) sg[i] = gfeat[g*384+i];
  if(t<64){
    float a = gf1_b[t];
    #pragma unroll
    for(int i=0;i<10;++i) a += gf[g*10+i]*gf1_w[i*64+t];
    hid1[t] = fmaxf(a,0.f);
  }
  __syncthreads();
  if(t<64){
    float a = gf2_b[t];
    for(int k=0;k<64;++k) a += hid1[k]*gf2_w[k*64+t];
    comb[128+t] = a;
  }
  {
    float a = gc_b[t];
    for(int k=0;k<384;++k) a += sg[k]*gc_w[k*128+t];
    comb[t] = fmaxf(a,0.f);
  }
  __syncthreads();
  {
    float a = p1_b[t];
    for(int k=0;k<192;++k) a += comb[k]*p1_w[k*128+t];
    r1[t] = fmaxf(a,0.f);
  }
  __syncthreads();
  if(t<64){
    float a = p2_b[t];
    for(int k=0;k<128;++k) a += r1[k]*p2_w[k*64+t];
    r2[t] = fmaxf(a,0.f);
  }
  __syncthreads();
  if(t<TOUT){
    float a = p3_b[t];
    for(int k=0;k<64;++k) a += r2[k]*p3_w[k*TOUT+t];
    out[g*TOUT+t] = a;
  }
}

extern "C" void kernel_launch(void* const* d_in, const int* in_sizes, int n_in,
                              void* d_out, int out_size, void* d_ws, size_t ws_size,
                              hipStream_t stream){
  (void)in_sizes; (void)n_in; (void)out_size; (void)ws_size;
  const float* x        = (const float*)d_in[0];
  const int*   ei       = (const int*)d_in[1];
  const float* ea       = (const float*)d_in[2];
  const int*   batch    = (const int*)d_in[3];
  const float* gfin     = (const float*)d_in[4];
  const float* node_w   = (const float*)d_in[5];
  const float* node_b   = (const float*)d_in[6];
  const float* edge_w   = (const float*)d_in[7];
  const float* edge_b   = (const float*)d_in[8];
  const float* gat_lin_w  = (const float*)d_in[9];
  const float* gat_edge_w = (const float*)d_in[10];
  const float* att_src  = (const float*)d_in[11];
  const float* att_dst  = (const float*)d_in[12];
  const float* att_edge = (const float*)d_in[13];
  const float* gat_bias = (const float*)d_in[14];
  const float* bn_gamma = (const float*)d_in[15];
  const float* bn_beta  = (const float*)d_in[16];
  const float* bn_mean  = (const float*)d_in[17];
  const float* bn_var   = (const float*)d_in[18];
  const float* gc_w = (const float*)d_in[19];
  const float* gc_b = (const float*)d_in[20];
  const float* gf1_w = (const float*)d_in[21];
  const float* gf1_b = (const float*)d_in[22];
  const float* gf2_w = (const float*)d_in[23];
  const float* gf2_b = (const float*)d_in[24];
  const float* p1_w = (const float*)d_in[25];
  const float* p1_b = (const float*)d_in[26];
  const float* p2_w = (const float*)d_in[27];
  const float* p2_b = (const float*)d_in[28];
  const float* p3_w = (const float*)d_in[29];
  const float* p3_b = (const float*)d_in[30];
  float* out = (float*)d_out;

  char* w = (char*)d_ws;
  size_t o = 0;
  auto carve = [&](size_t bytes)->char*{
    char* p = w + o; o += (bytes + 255) & ~(size_t)255; return p;
  };
  float* xh     = (float*)carve((size_t)N_NODES*HID*4);
  float* hbuf   = (float*)carve((size_t)N_NODES*HID*4);
  float* ae     = (float*)carve((size_t)N_EDGES*16*4);
  float* aeloop = (float*)carve((size_t)N_NODES*16*4);
  float* as_    = (float*)carve((size_t)N_NODES*4*4);
  float* ad_    = (float*)carve((size_t)N_NODES*4*4);
  int* deg      = (int*)carve((size_t)N_NODES*4);
  int* rowptr   = (int*)carve((size_t)(N_NODES+1)*4);
  int* fill     = (int*)carve((size_t)N_NODES*4);
  int* csr_src  = (int*)carve((size_t)N_EDGES*4);
  int* csr_eid  = (int*)carve((size_t)N_EDGES*4);
  int* part     = (int*)carve(1024*4);
  float* mebuf  = (float*)carve(64*4);
  unsigned short* whi = (unsigned short*)carve(65536*2);
  unsigned short* wlo = (unsigned short*)carve(65536*2);
  int* gptr     = (int*)carve((size_t)(N_GRAPHS+1)*4);
  float* gfeat  = (float*)carve((size_t)N_GRAPHS*384*4);

  hipMemsetAsync(deg, 0, (size_t)N_NODES*4, stream);
  hipMemsetAsync(aeloop, 0, (size_t)N_NODES*16*4, stream);
  hipMemsetAsync(fill, 0, (size_t)N_NODES*4, stream);

  k_prep<<<1,256,0,stream>>>(gat_edge_w, att_edge, edge_w, edge_b, mebuf);
  k_wswz<<<256,256,0,stream>>>(gat_lin_w, whi, wlo);
  k_hinit<<<N_NODES,128,0,stream>>>(x, node_w, node_b, hbuf);
  k_edge<<<(N_EDGES+255)/256,256,0,stream>>>(ei, ea, mebuf, ae, aeloop, deg);
  k_aediv<<<(N_NODES*16+255)/256,256,0,stream>>>(aeloop, deg);
  int nb = (N_NODES+1023)/1024;
  k_scan1<<<nb,256,0,stream>>>(deg, part);
  k_scan2<<<1,64,0,stream>>>(part, rowptr, nb);
  k_scan3<<<nb,256,0,stream>>>(deg, part, rowptr);
  k_fill<<<(N_EDGES+255)/256,256,0,stream>>>(ei, rowptr, fill, csr_src, csr_eid);

  for(int l=0;l<NLAYER;++l){
    k_gemm<<<(N_NODES+63)/64,256,0,stream>>>(hbuf, whi + l*16384, wlo + l*16384,
        att_src + l*128, att_dst + l*128, xh, as_, ad_);
    k_aggr<<<(N_NODES+3)/4,256,0,stream>>>(xh, as_, ad_, ae, aeloop, rowptr, csr_src, csr_eid,
        gat_bias + l*128, bn_gamma + l*128, bn_beta + l*128, bn_mean + l*128, bn_var + l*128,
        hbuf, l);
  }

  k_gptr<<<(N_GRAPHS+256)/256,256,0,stream>>>(batch, gptr);
  k_pool<<<N_GRAPHS,128,0,stream>>>(hbuf, gptr, gfeat);
  k_head<<<N_GRAPHS,128,0,stream>>>(gfeat, gfin, gc_w, gc_b, gf1_w, gf1_b, gf2_w, gf2_b,
        p1_w, p1_b, p2_w, p2_b, p3_w, p3_b, out);
}

// Round 2
// 757.773 us; speedup vs baseline: 1.6310x; 1.6310x over previous
//
#include <hip/hip_runtime.h>

#define N_NODES 100000
#define N_EDGES 400000
#define N_GRAPHS 2048
#define HID 128
#define NLAYER 4
#define TOUT 5
#define EPSV 1e-5f
#define SLOPE 0.2f

typedef float v4f __attribute__((ext_vector_type(4)));
typedef __bf16 v8bf __attribute__((ext_vector_type(8)));
typedef short v8s __attribute__((ext_vector_type(8)));

static __device__ __forceinline__ unsigned short f2bf_bits(float f){
  unsigned u = __builtin_bit_cast(unsigned, f);
  unsigned r = u + 0x7fffu + ((u >> 16) & 1u);
  return (unsigned short)(r >> 16);
}
static __device__ __forceinline__ float bfbits2f(unsigned short s){
  unsigned u = ((unsigned)s) << 16;
  return __builtin_bit_cast(float, u);
}

// h = x @ node_w + node_b
__global__ void k_hinit(const float* __restrict__ x, const float* __restrict__ nw,
                        const float* __restrict__ nb, float* __restrict__ hbuf){
  int n = blockIdx.x; int c = threadIdx.x;
  float acc = nb[c];
  #pragma unroll
  for(int f=0; f<7; ++f) acc += x[n*7+f]*nw[f*HID+c];
  hbuf[n*HID+c] = acc;
}

// small projection matrices: Me[3][16], be[16] such that a_e[e][l*4+h] = ea@Me + be
__global__ void k_prep(const float* __restrict__ gat_edge_w, const float* __restrict__ att_edge,
                       const float* __restrict__ edge_w, const float* __restrict__ edge_b,
                       float* __restrict__ mebuf){
  __shared__ float Ve[128*16];
  int t = threadIdx.x;
  for(int id=t; id<2048; id+=256){
    int k = id>>4, li = id&15, l = li>>2, hh = li&3;
    const float* gw = gat_edge_w + l*16384 + k*128 + hh*32;
    const float* at = att_edge + l*128 + hh*32;
    float s = 0.f;
    #pragma unroll
    for(int c=0;c<32;++c) s += gw[c]*at[c];
    Ve[k*16+li] = s;
  }
  __syncthreads();
  if(t < 48){
    int f = t>>4, li = t&15;
    float s=0.f;
    for(int k=0;k<128;++k) s += edge_w[f*128+k]*Ve[k*16+li];
    mebuf[f*16+li] = s;
  } else if (t < 64){
    int li = t-48; float s=0.f;
    for(int k=0;k<128;++k) s += edge_b[k]*Ve[k*16+li];
    mebuf[48+li] = s;
  }
}

// swizzle gat_lin_w into MFMA B-fragment order, split into bf16 hi/lo
__global__ void k_wswz(const float* __restrict__ W, unsigned short* __restrict__ whi,
                       unsigned short* __restrict__ wlo){
  int idx = blockIdx.x*256 + threadIdx.x; // 0..65535 == l*16384 + k*128 + c
  int l = idx>>14, k = (idx>>7)&127, c = idx&127;
  float w = W[idx];
  unsigned short hi = f2bf_bits(w);
  unsigned short lo = f2bf_bits(w - bfbits2f(hi));
  int kb=k>>5, quad=(k>>3)&3, j=k&7, cg=c>>4, r=c&15, lane=quad*16+r;
  int dst = ((l*4+kb)*8+cg)*512 + lane*8 + j;
  whi[dst]=hi; wlo[dst]=lo;
}

// per real edge: a_e for all 4 layers x 4 heads (NO atomics on float data)
__global__ void k_edge(const int* __restrict__ ei, const float* __restrict__ ea,
                       const float* __restrict__ mebuf, float* __restrict__ ae,
                       int* __restrict__ deg){
  int e = blockIdx.x*256 + threadIdx.x;
  if(e >= N_EDGES) return;
  int dst = ei[N_EDGES + e];
  float a0 = ea[e*3], a1 = ea[e*3+1], a2 = ea[e*3+2];
  float v[16];
  #pragma unroll
  for(int i=0;i<16;++i)
    v[i] = mebuf[48+i] + a0*mebuf[i] + a1*mebuf[16+i] + a2*mebuf[32+i];
  v4f* aeo = (v4f*)(ae + (size_t)e*16);
  #pragma unroll
  for(int q=0;q<4;++q){ v4f t = {v[q*4],v[q*4+1],v[q*4+2],v[q*4+3]}; aeo[q]=t; }
  atomicAdd(&deg[dst], 1);
}

// aeloop[n][16] = mean of ae over incoming edges (CSR, no atomics)
// 16 lanes per node
__global__ void k_aeloop(const float* __restrict__ ae, const int* __restrict__ rowptr,
                         const int* __restrict__ csr_eid, float* __restrict__ aeloop){
  int t = threadIdx.x;
  int node = blockIdx.x*16 + (t>>4);
  if(node >= N_NODES) return;
  int li = t & 15;
  int s = rowptr[node], e = rowptr[node+1];
  float acc = 0.f;
  for(int j=s;j<e;++j) acc += ae[(size_t)csr_eid[j]*16 + li];
  int d = e - s;
  aeloop[node*16+li] = acc / (float)(d>1?d:1);
}

// exclusive scan of deg -> rowptr (3 phases, chunk=1024)
__global__ void k_scan1(const int* __restrict__ deg, int* __restrict__ part){
  __shared__ int s[256];
  int t=threadIdx.x; int base = blockIdx.x*1024 + t*4;
  int sum=0;
  #pragma unroll
  for(int j=0;j<4;++j){ int i=base+j; sum += (i<N_NODES)? deg[i]:0; }
  s[t]=sum; __syncthreads();
  for(int off=128; off>0; off>>=1){ if(t<off) s[t]+=s[t+off]; __syncthreads(); }
  if(t==0) part[blockIdx.x]=s[0];
}
__global__ void k_scan2(int* __restrict__ part, int* __restrict__ rowptr, int nb){
  if(threadIdx.x==0 && blockIdx.x==0){
    int run=0;
    for(int i=0;i<nb;++i){ int v=part[i]; part[i]=run; run+=v; }
    rowptr[N_NODES]=run;
  }
}
__global__ void k_scan3(const int* __restrict__ deg, const int* __restrict__ part, int* __restrict__ rowptr){
  __shared__ int s[256];
  int t=threadIdx.x; int base = blockIdx.x*1024 + t*4;
  int v[4]; int sum=0; int pre[4];
  #pragma unroll
  for(int j=0;j<4;++j){ int i=base+j; v[j]=(i<N_NODES)?deg[i]:0; pre[j]=sum; sum+=v[j]; }
  s[t]=sum; __syncthreads();
  for(int off=1; off<256; off<<=1){
    int xv = (t>=off)? s[t-off]:0; __syncthreads();
    s[t]+=xv; __syncthreads();
  }
  int toff = (t>0)? s[t-1]:0;
  int g = part[blockIdx.x];
  #pragma unroll
  for(int j=0;j<4;++j){ int i=base+j; if(i<N_NODES) rowptr[i]=g+toff+pre[j]; }
}

__global__ void k_fill(const int* __restrict__ ei, const int* __restrict__ rowptr,
                       int* __restrict__ fill, int* __restrict__ csr_src, int* __restrict__ csr_eid){
  int e = blockIdx.x*256+threadIdx.x;
  if(e>=N_EDGES) return;
  int dst = ei[N_EDGES+e];
  int pos = rowptr[dst] + atomicAdd(&fill[dst],1);
  csr_src[pos] = ei[e];
  csr_eid[pos] = e;
}

// xh = h @ gat_lin_w[l]  (split-bf16 MFMA, fp32-class accuracy)
// epilogue: a_s[n,h], a_d[n,h] via quad shuffles
__global__ void k_gemm(const float* __restrict__ hbuf, const unsigned short* __restrict__ whi,
                       const unsigned short* __restrict__ wlo,
                       const float* __restrict__ att_src_l, const float* __restrict__ att_dst_l,
                       float* __restrict__ xh, float* __restrict__ as_, float* __restrict__ ad_){
  int wave = threadIdx.x>>6, lane = threadIdx.x&63;
  int row0 = blockIdx.x*64 + wave*16;
  if(row0 >= N_NODES) return;
  int q = lane>>4, r = lane&15;
  const float* hrow = hbuf + (size_t)(row0 + r)*HID;
  v8bf ahi[4], alo[4];
  #pragma unroll
  for(int kb=0;kb<4;++kb){
    const v4f* p = (const v4f*)(hrow + kb*32 + q*8);
    v4f f0 = p[0], f1 = p[1];
    #pragma unroll
    for(int j=0;j<4;++j){
      unsigned short hi = f2bf_bits(f0[j]);
      unsigned short lo = f2bf_bits(f0[j]-bfbits2f(hi));
      ahi[kb][j] = __builtin_bit_cast(__bf16, hi);
      alo[kb][j] = __builtin_bit_cast(__bf16, lo);
      unsigned short hi2 = f2bf_bits(f1[j]);
      unsigned short lo2 = f2bf_bits(f1[j]-bfbits2f(hi2));
      ahi[kb][j+4] = __builtin_bit_cast(__bf16, hi2);
      alo[kb][j+4] = __builtin_bit_cast(__bf16, lo2);
    }
  }
  v4f acc[8];
  #pragma unroll
  for(int cg=0;cg<8;++cg){
    v4f a = {0.f,0.f,0.f,0.f};
    #pragma unroll
    for(int kb=0;kb<4;++kb){
      v8bf bhi = __builtin_bit_cast(v8bf, *(const v8s*)(whi + ((kb*8+cg)*64 + lane)*8));
      v8bf blo = __builtin_bit_cast(v8bf, *(const v8s*)(wlo + ((kb*8+cg)*64 + lane)*8));
      a = __builtin_amdgcn_mfma_f32_16x16x32_bf16(ahi[kb], bhi, a, 0,0,0);
      a = __builtin_amdgcn_mfma_f32_16x16x32_bf16(ahi[kb], blo, a, 0,0,0);
      a = __builtin_amdgcn_mfma_f32_16x16x32_bf16(alo[kb], bhi, a, 0,0,0);
    }
    acc[cg]=a;
  }
  #pragma unroll
  for(int cg=0;cg<8;++cg){
    #pragma unroll
    for(int reg=0;reg<4;++reg)
      xh[(size_t)(row0 + q*4 + reg)*HID + cg*16 + r] = acc[cg][reg];
  }
  #pragma unroll
  for(int hh=0; hh<4; ++hh){
    float sl = att_src_l[hh*32 + r],  sh2 = att_src_l[hh*32+16+r];
    float dl = att_dst_l[hh*32 + r],  dh  = att_dst_l[hh*32+16+r];
    #pragma unroll
    for(int reg=0;reg<4;++reg){
      float vs = acc[2*hh][reg]*sl + acc[2*hh+1][reg]*sh2;
      float vd = acc[2*hh][reg]*dl + acc[2*hh+1][reg]*dh;
      vs += __shfl_xor(vs,1); vs += __shfl_xor(vs,2); vs += __shfl_xor(vs,4); vs += __shfl_xor(vs,8);
      vd += __shfl_xor(vd,1); vd += __shfl_xor(vd,2); vd += __shfl_xor(vd,4); vd += __shfl_xor(vd,8);
      if(r==0){
        int rr = row0 + q*4 + reg;
        as_[rr*4+hh] = vs;
        ad_[rr*4+hh] = vd;
      }
    }
  }
}

// wave-per-node: single-pass online softmax over incoming edges + self loop,
// aggregate xh, fused bias + BN + relu + residual, in-place h update
__global__ void k_aggr(const float* __restrict__ xh, const float* __restrict__ as_,
    const float* __restrict__ ad_, const float* __restrict__ ae, const float* __restrict__ aeloop,
    const int* __restrict__ rowptr, const int* __restrict__ csr_src, const int* __restrict__ csr_eid,
    const float* __restrict__ bias, const float* __restrict__ gamma, const float* __restrict__ beta,
    const float* __restrict__ mean, const float* __restrict__ var,
    float* __restrict__ hbuf, int layer){
  int node = blockIdx.x*4 + (threadIdx.x>>6);
  if(node >= N_NODES) return;
  int lane = threadIdx.x & 63;
  int h0 = lane>>5, h1 = 2+(lane>>5);
  int c0 = lane, c1 = lane+64;
  float ad0 = ad_[node*4+h0], ad1 = ad_[node*4+h1];
  float al0 = as_[node*4+h0] + ad0 + aeloop[node*16+layer*4+h0];
  float al1 = as_[node*4+h1] + ad1 + aeloop[node*16+layer*4+h1];
  al0 = al0>0.f ? al0 : SLOPE*al0;
  al1 = al1>0.f ? al1 : SLOPE*al1;
  int s = rowptr[node], e = rowptr[node+1];
  // self-loop seeds: weight exp(al-m)=1
  float m0=al0, m1=al1;
  float d0=1.f, d1=1.f;
  float acc0 = xh[(size_t)node*HID+c0], acc1 = xh[(size_t)node*HID+c1];
  for(int j=s;j<e;++j){
    int sr = csr_src[j]; int eid = csr_eid[j];
    float b0 = as_[sr*4+h0] + ad0 + ae[(size_t)eid*16+layer*4+h0];
    float b1 = as_[sr*4+h1] + ad1 + ae[(size_t)eid*16+layer*4+h1];
    b0 = b0>0.f?b0:SLOPE*b0; b1 = b1>0.f?b1:SLOPE*b1;
    float x0 = xh[(size_t)sr*HID+c0], x1 = xh[(size_t)sr*HID+c1];
    float nm0 = fmaxf(m0,b0), nm1 = fmaxf(m1,b1);
    float sc0 = __expf(m0-nm0), sc1 = __expf(m1-nm1);
    float e0 = __expf(b0-nm0),  e1 = __expf(b1-nm1);
    d0 = d0*sc0 + e0; d1 = d1*sc1 + e1;
    acc0 = acc0*sc0 + e0*x0; acc1 = acc1*sc1 + e1*x1;
    m0 = nm0; m1 = nm1;
  }
  float o0 = acc0/d0 + bias[c0];
  float o1 = acc1/d1 + bias[c1];
  o0 = (o0-mean[c0])*gamma[c0]*rsqrtf(var[c0]+EPSV)+beta[c0];
  o1 = (o1-mean[c1])*gamma[c1]*rsqrtf(var[c1]+EPSV)+beta[c1];
  float n0 = fmaxf(o0,0.f)+hbuf[(size_t)node*HID+c0];
  float n1 = fmaxf(o1,0.f)+hbuf[(size_t)node*HID+c1];
  hbuf[(size_t)node*HID+c0]=n0; hbuf[(size_t)node*HID+c1]=n1;
}

__global__ void k_gptr(const int* __restrict__ batch, int* __restrict__ gptr){
  int g = blockIdx.x*256+threadIdx.x;
  if(g > N_GRAPHS) return;
  int lo=0, hi=N_NODES;
  while(lo<hi){ int mid=(lo+hi)>>1; if(batch[mid] < g) lo=mid+1; else hi=mid; }
  gptr[g]=lo;
}

__global__ void k_pool(const float* __restrict__ hbuf, const int* __restrict__ gptr,
                       float* __restrict__ gfeat){
  int g = blockIdx.x, c = threadIdx.x;
  int s = gptr[g], e = gptr[g+1];
  float sum=0.f, mx=-3.4e38f;
  for(int i=s;i<e;++i){ float v = hbuf[(size_t)i*HID+c]; sum+=v; mx=fmaxf(mx,v); }
  int cnt = e-s;
  float meanv = sum / (float)(cnt>1?cnt:1);
  if(cnt==0) mx=0.f;
  gfeat[g*384 + c] = meanv;
  gfeat[g*384 + 128 + c] = mx;
  gfeat[g*384 + 256 + c] = sum;
}

__global__ void k_head(const float* __restrict__ gfeat, const float* __restrict__ gf,
   const float* __restrict__ gc_w, const float* __restrict__ gc_b,
   const float* __restrict__ gf1_w, const float* __restrict__ gf1_b,
   const float* __restrict__ gf2_w, const float* __restrict__ gf2_b,
   const float* __restrict__ p1_w, const float* __restrict__ p1_b,
   const float* __restrict__ p2_w, const float* __restrict__ p2_b,
   const float* __restrict__ p3_w, const float* __restrict__ p3_b,
   float* __restrict__ out){
  __shared__ float sg[384];
  __shared__ float comb[192];
  __shared__ float hid1[64];
  __shared__ float r1[128];
  __shared__ float r2[64];
  int g = blockIdx.x, t = threadIdx.x;
  for(int i=t;i<384;i+=128) sg[i] = gfeat[g*384+i];
  if(t<64){
    float a = gf1_b[t];
    #pragma unroll
    for(int i=0;i<10;++i) a += gf[g*10+i]*gf1_w[i*64+t];
    hid1[t] = fmaxf(a,0.f);
  }
  __syncthreads();
  if(t<64){
    float a = gf2_b[t];
    for(int k=0;k<64;++k) a += hid1[k]*gf2_w[k*64+t];
    comb[128+t] = a;
  }
  {
    float a = gc_b[t];
    for(int k=0;k<384;++k) a += sg[k]*gc_w[k*128+t];
    comb[t] = fmaxf(a,0.f);
  }
  __syncthreads();
  {
    float a = p1_b[t];
    for(int k=0;k<192;++k) a += comb[k]*p1_w[k*128+t];
    r1[t] = fmaxf(a,0.f);
  }
  __syncthreads();
  if(t<64){
    float a = p2_b[t];
    for(int k=0;k<128;++k) a += r1[k]*p2_w[k*64+t];
    r2[t] = fmaxf(a,0.f);
  }
  __syncthreads();
  if(t<TOUT){
    float a = p3_b[t];
    for(int k=0;k<64;++k) a += r2[k]*p3_w[k*TOUT+t];
    out[g*TOUT+t] = a;
  }
}

extern "C" void kernel_launch(void* const* d_in, const int* in_sizes, int n_in,
                              void* d_out, int out_size, void* d_ws, size_t ws_size,
                              hipStream_t stream){
  (void)in_sizes; (void)n_in; (void)out_size; (void)ws_size;
  const float* x        = (const float*)d_in[0];
  const int*   ei       = (const int*)d_in[1];
  const float* ea       = (const float*)d_in[2];
  const int*   batch    = (const int*)d_in[3];
  const float* gfin     = (const float*)d_in[4];
  const float* node_w   = (const float*)d_in[5];
  const float* node_b   = (const float*)d_in[6];
  const float* edge_w   = (const float*)d_in[7];
  const float* edge_b   = (const float*)d_in[8];
  const float* gat_lin_w  = (const float*)d_in[9];
  const float* gat_edge_w = (const float*)d_in[10];
  const float* att_src  = (const float*)d_in[11];
  const float* att_dst  = (const float*)d_in[12];
  const float* att_edge = (const float*)d_in[13];
  const float* gat_bias = (const float*)d_in[14];
  const float* bn_gamma = (const float*)d_in[15];
  const float* bn_beta  = (const float*)d_in[16];
  const float* bn_mean  = (const float*)d_in[17];
  const float* bn_var   = (const float*)d_in[18];
  const float* gc_w = (const float*)d_in[19];
  const float* gc_b = (const float*)d_in[20];
  const float* gf1_w = (const float*)d_in[21];
  const float* gf1_b = (const float*)d_in[22];
  const float* gf2_w = (const float*)d_in[23];
  const float* gf2_b = (const float*)d_in[24];
  const float* p1_w = (const float*)d_in[25];
  const float* p1_b = (const float*)d_in[26];
  const float* p2_w = (const float*)d_in[27];
  const float* p2_b = (const float*)d_in[28];
  const float* p3_w = (const float*)d_in[29];
  const float* p3_b = (const float*)d_in[30];
  float* out = (float*)d_out;

  char* w = (char*)d_ws;
  size_t o = 0;
  auto carve = [&](size_t bytes)->char*{
    char* p = w + o; o += (bytes + 255) & ~(size_t)255; return p;
  };
  float* xh     = (float*)carve((size_t)N_NODES*HID*4);
  float* hbuf   = (float*)carve((size_t)N_NODES*HID*4);
  float* ae     = (float*)carve((size_t)N_EDGES*16*4);
  float* aeloop = (float*)carve((size_t)N_NODES*16*4);
  float* as_    = (float*)carve((size_t)N_NODES*4*4);
  float* ad_    = (float*)carve((size_t)N_NODES*4*4);
  int* deg      = (int*)carve((size_t)N_NODES*4);
  int* rowptr   = (int*)carve((size_t)(N_NODES+1)*4);
  int* fill     = (int*)carve((size_t)N_NODES*4);
  int* csr_src  = (int*)carve((size_t)N_EDGES*4);
  int* csr_eid  = (int*)carve((size_t)N_EDGES*4);
  int* part     = (int*)carve(1024*4);
  float* mebuf  = (float*)carve(64*4);
  unsigned short* whi = (unsigned short*)carve(65536*2);
  unsigned short* wlo = (unsigned short*)carve(65536*2);
  int* gptr     = (int*)carve((size_t)(N_GRAPHS+1)*4);
  float* gfeat  = (float*)carve((size_t)N_GRAPHS*384*4);

  hipMemsetAsync(deg, 0, (size_t)N_NODES*4, stream);
  hipMemsetAsync(fill, 0, (size_t)N_NODES*4, stream);

  k_prep<<<1,256,0,stream>>>(gat_edge_w, att_edge, edge_w, edge_b, mebuf);
  k_wswz<<<256,256,0,stream>>>(gat_lin_w, whi, wlo);
  k_hinit<<<N_NODES,128,0,stream>>>(x, node_w, node_b, hbuf);
  k_edge<<<(N_EDGES+255)/256,256,0,stream>>>(ei, ea, mebuf, ae, deg);
  int nb = (N_NODES+1023)/1024;
  k_scan1<<<nb,256,0,stream>>>(deg, part);
  k_scan2<<<1,64,0,stream>>>(part, rowptr, nb);
  k_scan3<<<nb,256,0,stream>>>(deg, part, rowptr);
  k_fill<<<(N_EDGES+255)/256,256,0,stream>>>(ei, rowptr, fill, csr_src, csr_eid);
  k_aeloop<<<(N_NODES+15)/16,256,0,stream>>>(ae, rowptr, csr_eid, aeloop);

  for(int l=0;l<NLAYER;++l){
    k_gemm<<<(N_NODES+63)/64,256,0,stream>>>(hbuf, whi + l*16384, wlo + l*16384,
        att_src + l*128, att_dst + l*128, xh, as_, ad_);
    k_aggr<<<(N_NODES+3)/4,256,0,stream>>>(xh, as_, ad_, ae, aeloop, rowptr, csr_src, csr_eid,
        gat_bias + l*128, bn_gamma + l*128, bn_beta + l*128, bn_mean + l*128, bn_var + l*128,
        hbuf, l);
  }

  k_gptr<<<(N_GRAPHS+256)/256,256,0,stream>>>(batch, gptr);
  k_pool<<<N_GRAPHS,128,0,stream>>>(hbuf, gptr, gfeat);
  k_head<<<N_GRAPHS,128,0,stream>>>(gfeat, gfin, gc_w, gc_b, gf1_w, gf1_b, gf2_w, gf2_b,
        p1_w, p1_b, p2_w, p2_b, p3_w, p3_b, out);
}